// Round 1
// baseline (207.395 us; speedup 1.0000x reference)
//
#include <hip/hip_runtime.h>

// LBP uniform P=8 R=1 on (32,3,512,512) f32, zero-padded borders.
// Memory-bound stencil: each thread computes a float4 (4 horizontal pixels).
// Circular neighbor order (dy,dx): (-1,-1),(-1,0),(-1,1),(0,1),(1,1),(1,0),(1,-1),(0,-1)

#define LBP_H 512
#define LBP_W 512

__device__ __forceinline__ float lbp_quant(float v) {
    // == jnp.clip(jnp.floor(x*255), 0, 255) in exact fp32 arithmetic
    return fminf(fmaxf(floorf(v * 255.0f), 0.0f), 255.0f);
}

__global__ __launch_bounds__(256) void lbp_kernel(const float* __restrict__ x,
                                                  float* __restrict__ out,
                                                  int total4) {
    int idx = blockIdx.x * blockDim.x + threadIdx.x;
    if (idx >= total4) return;

    const int col4  = idx & (LBP_W / 4 - 1);   // 0..127
    const int rowg  = idx >> 7;                // global row across all planes
    const int i     = rowg & (LBP_H - 1);      // row within plane
    const int plane = rowg >> 9;               // b*C + c
    const int j0    = col4 << 2;               // leading column of this float4

    const float* base = x + (size_t)plane * (LBP_H * LBP_W);

    // q[r][k] = quantized value at (i-1+r, j0-1+k), zero outside the image
    float q[3][6];
#pragma unroll
    for (int r = 0; r < 3; ++r) {
        const int ri = i - 1 + r;
        if (ri < 0 || ri >= LBP_H) {
#pragma unroll
            for (int k = 0; k < 6; ++k) q[r][k] = 0.0f;
        } else {
            const float* rp = base + ri * LBP_W + j0;
            const float4 v = *(const float4*)rp;            // aligned 16B
            const float lft = (j0 > 0)            ? rp[-1] : 0.0f;
            const float rgt = (j0 + 4 < LBP_W)    ? rp[4]  : 0.0f;
            q[r][0] = lbp_quant(lft);
            q[r][1] = lbp_quant(v.x);
            q[r][2] = lbp_quant(v.y);
            q[r][3] = lbp_quant(v.z);
            q[r][4] = lbp_quant(v.w);
            q[r][5] = lbp_quant(rgt);
        }
    }

    float4 o;
    float* op = &o.x;
#pragma unroll
    for (int p = 0; p < 4; ++p) {
        const float c = q[1][p + 1];
        // circular order per _OFFSETS
        const int b0 = q[0][p]     >= c;   // (-1,-1)
        const int b1 = q[0][p + 1] >= c;   // (-1, 0)
        const int b2 = q[0][p + 2] >= c;   // (-1, 1)
        const int b3 = q[1][p + 2] >= c;   // ( 0, 1)
        const int b4 = q[2][p + 2] >= c;   // ( 1, 1)
        const int b5 = q[2][p + 1] >= c;   // ( 1, 0)
        const int b6 = q[2][p]     >= c;   // ( 1,-1)
        const int b7 = q[1][p]     >= c;   // ( 0,-1)

        const int ones  = b0 + b1 + b2 + b3 + b4 + b5 + b6 + b7;
        const int trans = (b0 ^ b7) + (b1 ^ b0) + (b2 ^ b1) + (b3 ^ b2) +
                          (b4 ^ b3) + (b5 ^ b4) + (b6 ^ b5) + (b7 ^ b6);
        const int lbp = (trans <= 2) ? ones : 9;
        op[p] = (float)lbp * (1.0f / 255.0f);
    }

    *(float4*)(out + (size_t)rowg * LBP_W + j0) = o;
}

extern "C" void kernel_launch(void* const* d_in, const int* in_sizes, int n_in,
                              void* d_out, int out_size, void* d_ws, size_t ws_size,
                              hipStream_t stream) {
    const float* x = (const float*)d_in[0];
    float* out = (float*)d_out;
    const int total4 = out_size / 4;            // 6,291,456
    const int threads = 256;
    const int blocks = (total4 + threads - 1) / threads;  // 24,576
    lbp_kernel<<<blocks, threads, 0, stream>>>(x, out, total4);
}

// Round 2
// 190.208 us; speedup vs baseline: 1.0904x; 1.0904x over previous
//
#include <hip/hip_runtime.h>

// LBP uniform P=8 R=1 on (32,3,512,512) f32, zero-padded borders.
// R2: 4x4 output tile per thread; quantize each input value ONCE; edge
// columns via wave shuffles of quantized neighbors (lanes 0/63 masked load).
// Per-pixel: 8-bit mask + popcount(m ^ rot(m)) for transitions.

#define LBP_H 512
#define LBP_W 512
#define NPLANES 96           // 32 * 3

__device__ __forceinline__ float lbp_quant(float v) {
    // == jnp.clip(jnp.floor(x*255), 0, 255) in exact fp32 arithmetic
    return fminf(fmaxf(floorf(v * 255.0f), 0.0f), 255.0f);
}

__global__ __launch_bounds__(256) void lbp_kernel(const float* __restrict__ x,
                                                  float* __restrict__ out) {
    const int idx  = blockIdx.x * blockDim.x + threadIdx.x;
    const int col4  = idx & 127;          // 0..127  (columns j0..j0+3)
    const int rowg  = (idx >> 7) & 127;   // 0..127  (rows r0..r0+3)
    const int plane = idx >> 14;          // 0..95   (b*C + c)
    const int j0 = col4 << 2;
    const int r0 = rowg << 2;
    const int lane = threadIdx.x & 63;    // wave is uniform in (rowg, plane)

    const float* base  = x   + (size_t)plane * (LBP_H * LBP_W);
    float*       obase = out + (size_t)plane * (LBP_H * LBP_W);

    // e[r][k]: quantized value at input row r0-1+r (r=0..5), col j0-1+k (k=0..5)
    float e[6][6];
#pragma unroll
    for (int r = 0; r < 6; ++r) {
        const int ri = r0 - 1 + r;
        if (ri < 0 || ri >= LBP_H) {          // wave-uniform branch
#pragma unroll
            for (int k = 0; k < 6; ++k) e[r][k] = 0.0f;
        } else {
            const float* rp = base + ri * LBP_W + j0;
            const float4 v = *(const float4*)rp;   // aligned 16B, coalesced
            const float q1 = lbp_quant(v.x);
            const float q2 = lbp_quant(v.y);
            const float q3 = lbp_quant(v.z);
            const float q4 = lbp_quant(v.w);
            // neighbor-lane edges (full wave executes the shuffles)
            float lf = __shfl_up(q4, 1);    // lane i <- lane i-1's q4
            float rt = __shfl_down(q1, 1);  // lane i <- lane i+1's q1
            if (lane == 0)  lf = (j0 > 0)            ? lbp_quant(rp[-1]) : 0.0f;
            if (lane == 63) rt = (j0 + 4 < LBP_W)    ? lbp_quant(rp[4])  : 0.0f;
            e[r][0] = lf;
            e[r][1] = q1; e[r][2] = q2; e[r][3] = q3; e[r][4] = q4;
            e[r][5] = rt;
        }
    }

#pragma unroll
    for (int p = 0; p < 4; ++p) {             // output row r0+p
        float4 o;
        float* op = &o.x;
#pragma unroll
        for (int c = 0; c < 4; ++c) {         // output col j0+c
            const float ctr = e[p + 1][c + 1];
            // circular order: (-1,-1),(-1,0),(-1,1),(0,1),(1,1),(1,0),(1,-1),(0,-1)
            unsigned m = 0u;
            m |= (e[p    ][c    ] >= ctr) ?   1u : 0u;
            m |= (e[p    ][c + 1] >= ctr) ?   2u : 0u;
            m |= (e[p    ][c + 2] >= ctr) ?   4u : 0u;
            m |= (e[p + 1][c + 2] >= ctr) ?   8u : 0u;
            m |= (e[p + 2][c + 2] >= ctr) ?  16u : 0u;
            m |= (e[p + 2][c + 1] >= ctr) ?  32u : 0u;
            m |= (e[p + 2][c    ] >= ctr) ?  64u : 0u;
            m |= (e[p + 1][c    ] >= ctr) ? 128u : 0u;
            const unsigned rot = ((m >> 1) | (m << 7)) & 255u;
            const int trans = __popc(m ^ rot);
            const int val = (trans <= 2) ? __popc(m) : 9;
            op[c] = (float)val * (1.0f / 255.0f);
        }
        *(float4*)(obase + (size_t)(r0 + p) * LBP_W + j0) = o;
    }
}

extern "C" void kernel_launch(void* const* d_in, const int* in_sizes, int n_in,
                              void* d_out, int out_size, void* d_ws, size_t ws_size,
                              hipStream_t stream) {
    const float* x = (const float*)d_in[0];
    float* out = (float*)d_out;
    const int total = NPLANES * 128 * 128;        // 1,572,864 threads (16 px each)
    const int threads = 256;
    const int blocks = total / threads;           // 6144
    lbp_kernel<<<blocks, threads, 0, stream>>>(x, out);
}

// Round 3
// 171.661 us; speedup vs baseline: 1.2082x; 1.1080x over previous
//
#include <hip/hip_runtime.h>

// LBP uniform P=8 R=1 on (32,3,512,512) f32, zero-padded borders.
// R3: 4x4 output tile per thread. ALL 18 global loads (6 float4 rows + 12
// clamped edge scalars) issued back-to-back with no intervening dependent
// ops -> single vmcnt latency exposure per thread (R2 had 6 serialized
// chains via per-row branch+shuffle). Bounds handled by address clamping +
// zero-masking after the loads. No shuffles, no lgkm chains.

#define LBP_H 512
#define LBP_W 512
#define NPLANES 96           // 32 * 3

__device__ __forceinline__ float lbp_quant(float v) {
    // == jnp.clip(jnp.floor(x*255), 0, 255) in exact fp32 arithmetic
    return fminf(fmaxf(floorf(v * 255.0f), 0.0f), 255.0f);
}

__global__ __launch_bounds__(256) void lbp_kernel(const float* __restrict__ x,
                                                  float* __restrict__ out) {
    const int idx  = blockIdx.x * blockDim.x + threadIdx.x;
    const int col4  = idx & 127;          // 0..127  (columns j0..j0+3)
    const int rowg  = (idx >> 7) & 127;   // 0..127  (rows r0..r0+3)
    const int plane = idx >> 14;          // 0..95   (b*C + c)
    const int j0 = col4 << 2;
    const int r0 = rowg << 2;

    const float* base  = x   + (size_t)plane * (LBP_H * LBP_W);
    float*       obase = out + (size_t)plane * (LBP_H * LBP_W);

    const int jm1 = (j0 > 0)           ? j0 - 1 : 0;        // clamped left col
    const int jp4 = (j0 + 4 < LBP_W)   ? j0 + 4 : LBP_W - 1; // clamped right col
    const bool lok = (j0 > 0);
    const bool rok = (j0 + 4 < LBP_W);

    // ---- phase 1: issue ALL loads, addresses clamped, no dependent ALU ----
    float4 v[6];
    float lf[6], rt[6];
#pragma unroll
    for (int r = 0; r < 6; ++r) {
        int ri = r0 - 1 + r;
        int ric = ri < 0 ? 0 : (ri >= LBP_H ? LBP_H - 1 : ri);
        const float* rp = base + ric * LBP_W;
        v[r]  = *(const float4*)(rp + j0);   // aligned 16B, coalesced
        lf[r] = rp[jm1];
        rt[r] = rp[jp4];
    }

    // ---- phase 2: quantize once per value, mask out-of-image to 0 ----
    // e[r][k]: quantized value at input row r0-1+r, col j0-1+k (0 outside)
    float e[6][6];
#pragma unroll
    for (int r = 0; r < 6; ++r) {
        const int ri = r0 - 1 + r;
        const bool rv = (ri >= 0) && (ri < LBP_H);
        e[r][0] = (rv && lok) ? lbp_quant(lf[r]) : 0.0f;
        e[r][1] = rv ? lbp_quant(v[r].x) : 0.0f;
        e[r][2] = rv ? lbp_quant(v[r].y) : 0.0f;
        e[r][3] = rv ? lbp_quant(v[r].z) : 0.0f;
        e[r][4] = rv ? lbp_quant(v[r].w) : 0.0f;
        e[r][5] = (rv && rok) ? lbp_quant(rt[r]) : 0.0f;
    }

    // ---- phase 3: 16 LBP codes ----
#pragma unroll
    for (int p = 0; p < 4; ++p) {             // output row r0+p
        float4 o;
        float* op = &o.x;
#pragma unroll
        for (int c = 0; c < 4; ++c) {         // output col j0+c
            const float ctr = e[p + 1][c + 1];
            // circular order: (-1,-1),(-1,0),(-1,1),(0,1),(1,1),(1,0),(1,-1),(0,-1)
            unsigned m = 0u;
            m |= (e[p    ][c    ] >= ctr) ?   1u : 0u;
            m |= (e[p    ][c + 1] >= ctr) ?   2u : 0u;
            m |= (e[p    ][c + 2] >= ctr) ?   4u : 0u;
            m |= (e[p + 1][c + 2] >= ctr) ?   8u : 0u;
            m |= (e[p + 2][c + 2] >= ctr) ?  16u : 0u;
            m |= (e[p + 2][c + 1] >= ctr) ?  32u : 0u;
            m |= (e[p + 2][c    ] >= ctr) ?  64u : 0u;
            m |= (e[p + 1][c    ] >= ctr) ? 128u : 0u;
            const unsigned rot = ((m >> 1) | (m << 7)) & 255u;
            const int trans = __popc(m ^ rot);
            const int val = (trans <= 2) ? __popc(m) : 9;
            op[c] = (float)val * (1.0f / 255.0f);
        }
        *(float4*)(obase + (size_t)(r0 + p) * LBP_W + j0) = o;
    }
}

extern "C" void kernel_launch(void* const* d_in, const int* in_sizes, int n_in,
                              void* d_out, int out_size, void* d_ws, size_t ws_size,
                              hipStream_t stream) {
    const float* x = (const float*)d_in[0];
    float* out = (float*)d_out;
    const int total = NPLANES * 128 * 128;        // 1,572,864 threads (16 px each)
    const int threads = 256;
    const int blocks = total / threads;           // 6144
    lbp_kernel<<<blocks, threads, 0, stream>>>(x, out);
}